// Round 2
// baseline (2202.244 us; speedup 1.0000x reference)
//
#include <hip/hip_runtime.h>
#include <math.h>

#define D_MODEL 1024
#define D_STATE 16
#define D_CONV  4
#define D_INNER 2048
#define DT_RANK 64
#define BATCH   2
#define SEQ     2048
#define M_ROWS  (BATCH * SEQ)   // 4096

__device__ __forceinline__ float softplusf(float x) {
    return (x > 20.f) ? x : log1pf(__expf(x));
}
__device__ __forceinline__ float siluf(float x) {
    return x * (1.f / (1.f + __expf(-x)));
}

// ---------------------------------------------------------------------------
// Generic fp32 GEMM: C(M x N) = A(M x K, lda) @ W(N x K, ldw)^T
// 128x128 tile, BK=32, 256 threads, 8x8 per thread as (4+4)x(4+4).
// EPI 0: plain store. EPI 1: softplus(acc + bias[col]).
// Requires M%128==0, N%128==0, K%32==0.
// ---------------------------------------------------------------------------
template <int EPI>
__global__ __launch_bounds__(256, 2)
void gemm_tile128(const float* __restrict__ A, int lda,
                  const float* __restrict__ W, int ldw,
                  float* __restrict__ C, int ldc,
                  int K, const float* __restrict__ bias)
{
    __shared__ float As[32][132];   // [k][m], +4 pad keeps 16B align, spreads banks
    __shared__ float Ws[32][132];   // [k][n]

    const int tid = threadIdx.x;
    const int tx = tid & 15;        // n-group
    const int ty = tid >> 4;        // m-group
    const int m0 = blockIdx.y * 128;
    const int n0 = blockIdx.x * 128;

    float acc[2][2][4][4];
#pragma unroll
    for (int im = 0; im < 2; ++im)
#pragma unroll
        for (int jm = 0; jm < 2; ++jm)
#pragma unroll
            for (int i = 0; i < 4; ++i)
#pragma unroll
                for (int j = 0; j < 4; ++j) acc[im][jm][i][j] = 0.f;

    for (int k0 = 0; k0 < K; k0 += 32) {
        // stage A-tile and W-tile (128 rows x 32 k) into LDS, transposed to [k][row]
#pragma unroll
        for (int i = 0; i < 4; ++i) {
            const int idx = tid + i * 256;     // 0..1023 float4 slots
            const int r  = idx >> 3;           // 0..127
            const int c4 = idx & 7;            // 0..7  (k-offset = c4*4)
            const float4 va = *(const float4*)(A + (size_t)(m0 + r) * lda + (k0 + c4 * 4));
            As[c4 * 4 + 0][r] = va.x;
            As[c4 * 4 + 1][r] = va.y;
            As[c4 * 4 + 2][r] = va.z;
            As[c4 * 4 + 3][r] = va.w;
            const float4 vw = *(const float4*)(W + (size_t)(n0 + r) * ldw + (k0 + c4 * 4));
            Ws[c4 * 4 + 0][r] = vw.x;
            Ws[c4 * 4 + 1][r] = vw.y;
            Ws[c4 * 4 + 2][r] = vw.z;
            Ws[c4 * 4 + 3][r] = vw.w;
        }
        __syncthreads();

#pragma unroll
        for (int kk = 0; kk < 32; ++kk) {
            float a[2][4], bfr[2][4];
            *(float4*)&a[0][0]   = *(const float4*)&As[kk][ty * 4];
            *(float4*)&a[1][0]   = *(const float4*)&As[kk][64 + ty * 4];
            *(float4*)&bfr[0][0] = *(const float4*)&Ws[kk][tx * 4];
            *(float4*)&bfr[1][0] = *(const float4*)&Ws[kk][64 + tx * 4];
#pragma unroll
            for (int im = 0; im < 2; ++im)
#pragma unroll
                for (int i = 0; i < 4; ++i)
#pragma unroll
                    for (int jm = 0; jm < 2; ++jm)
#pragma unroll
                        for (int j = 0; j < 4; ++j)
                            acc[im][jm][i][j] = fmaf(a[im][i], bfr[jm][j], acc[im][jm][i][j]);
        }
        __syncthreads();
    }

    // epilogue
#pragma unroll
    for (int im = 0; im < 2; ++im) {
#pragma unroll
        for (int i = 0; i < 4; ++i) {
            const int row = m0 + im * 64 + ty * 4 + i;
#pragma unroll
            for (int jm = 0; jm < 2; ++jm) {
                const int col = n0 + jm * 64 + tx * 4;
                float4 v;
                v.x = acc[im][jm][i][0];
                v.y = acc[im][jm][i][1];
                v.z = acc[im][jm][i][2];
                v.w = acc[im][jm][i][3];
                if (EPI == 1) {
                    v.x = softplusf(v.x + bias[col + 0]);
                    v.y = softplusf(v.y + bias[col + 1]);
                    v.z = softplusf(v.z + bias[col + 2]);
                    v.w = softplusf(v.w + bias[col + 3]);
                }
                *(float4*)(C + (size_t)row * ldc + col) = v;
            }
        }
    }
}

// ---------------------------------------------------------------------------
// Depthwise causal conv1d (taps=4, left pad 3) + silu.
// Reads x_in = xz[:, 0:2048] (row stride 4096), writes x_ssm (M x 2048).
// ---------------------------------------------------------------------------
__global__ __launch_bounds__(256)
void conv_silu_kernel(const float* __restrict__ xz,
                      const float* __restrict__ cw,
                      const float* __restrict__ cb,
                      float* __restrict__ xssm)
{
    const int idx = blockIdx.x * 256 + threadIdx.x;  // over M_ROWS * D_INNER
    const int d  = idx & (D_INNER - 1);
    const int bt = idx >> 11;
    const int t  = bt & (SEQ - 1);
    const float* p = xz + (size_t)bt * 4096 + d;     // x_in[bt][d]
    const float w0 = cw[d * 4 + 0], w1 = cw[d * 4 + 1];
    const float w2 = cw[d * 4 + 2], w3 = cw[d * 4 + 3];
    float acc = cb[d] + w3 * p[0];                   // w[k] multiplies x[t+k-3]
    if (t >= 1) acc += w2 * p[-4096];
    if (t >= 2) acc += w1 * p[-8192];
    if (t >= 3) acc += w0 * p[-12288];
    xssm[idx] = siluf(acc);
}

// ---------------------------------------------------------------------------
// proj(M x 96) = x_ssm(M x 2048) @ x_proj_w(96 x 2048)^T
// BM=64, BN=96, BK=32; 256 threads; thread = 4 rows x 6 cols.
// ---------------------------------------------------------------------------
__global__ __launch_bounds__(256, 2)
void gemm_proj_kernel(const float* __restrict__ A,
                      const float* __restrict__ W,
                      float* __restrict__ C)
{
    __shared__ float As[32][68];
    __shared__ float Ws[32][100];
    const int tid = threadIdx.x;
    const int tx = tid & 15;   // cols tx*6 .. +5
    const int ty = tid >> 4;   // rows ty*4 .. +3
    const int m0 = blockIdx.x * 64;

    float acc[4][6];
#pragma unroll
    for (int i = 0; i < 4; ++i)
#pragma unroll
        for (int j = 0; j < 6; ++j) acc[i][j] = 0.f;

    for (int k0 = 0; k0 < 2048; k0 += 32) {
#pragma unroll
        for (int i = 0; i < 2; ++i) {               // A: 64x32 = 512 float4
            const int idx = tid + i * 256;
            const int r = idx >> 3, c4 = idx & 7;
            const float4 v = *(const float4*)(A + (size_t)(m0 + r) * 2048 + k0 + c4 * 4);
            As[c4 * 4 + 0][r] = v.x;
            As[c4 * 4 + 1][r] = v.y;
            As[c4 * 4 + 2][r] = v.z;
            As[c4 * 4 + 3][r] = v.w;
        }
#pragma unroll
        for (int i = 0; i < 3; ++i) {               // W: 96x32 = 768 float4
            const int idx = tid + i * 256;
            const int r = idx >> 3, c4 = idx & 7;   // r 0..95
            const float4 v = *(const float4*)(W + (size_t)r * 2048 + k0 + c4 * 4);
            Ws[c4 * 4 + 0][r] = v.x;
            Ws[c4 * 4 + 1][r] = v.y;
            Ws[c4 * 4 + 2][r] = v.z;
            Ws[c4 * 4 + 3][r] = v.w;
        }
        __syncthreads();
#pragma unroll
        for (int kk = 0; kk < 32; ++kk) {
            float a[4];
            *(float4*)a = *(const float4*)&As[kk][ty * 4];
            float bv[6];
#pragma unroll
            for (int j = 0; j < 6; ++j) bv[j] = Ws[kk][tx * 6 + j];
#pragma unroll
            for (int i = 0; i < 4; ++i)
#pragma unroll
                for (int j = 0; j < 6; ++j) acc[i][j] = fmaf(a[i], bv[j], acc[i][j]);
        }
        __syncthreads();
    }
#pragma unroll
    for (int i = 0; i < 4; ++i)
#pragma unroll
        for (int j = 0; j < 6; ++j)
            C[(size_t)(m0 + ty * 4 + i) * 96 + tx * 6 + j] = acc[i][j];
}

// ---------------------------------------------------------------------------
// Selective scan, fused with skip (u*D) and silu(z) gate.
// Thread per (b,d): 16 states in registers. delta_y is delta on input and
// y on output (in-place; safe: each thread owns its column, writes trail reads).
// Vector streams (delta/u/z) double-buffer-prefetched 8 steps ahead.
// B/C loads are wave-uniform -> scalar loads.
// ---------------------------------------------------------------------------
#define UN 8
__global__ __launch_bounds__(256)
void scan_kernel(float* __restrict__ delta_y,
                 const float* __restrict__ xssm,
                 const float* __restrict__ proj,
                 const float* __restrict__ xz,
                 const float* __restrict__ A_log,
                 const float* __restrict__ Dvec)
{
    const int b = blockIdx.x >> 3;                       // uniform per block
    const int d = ((blockIdx.x & 7) << 8) + threadIdx.x; // 0..2047

    float Areg[16], h[16];
#pragma unroll
    for (int n = 0; n < 16; ++n) {
        Areg[n] = -__expf(A_log[d * 16 + n]);
        h[n] = 0.f;
    }
    const float Dd = Dvec[d];

    float* __restrict__ dyp      = delta_y + (size_t)b * SEQ * D_INNER + d;
    const float* __restrict__ up = xssm    + (size_t)b * SEQ * D_INNER + d;
    const float* __restrict__ zp = xz      + (size_t)b * SEQ * 4096 + 2048 + d;
    const float* __restrict__ pr = proj    + (size_t)b * SEQ * 96;

    float dlA[UN], uuA[UN], zzA[UN], dlB[UN], uuB[UN], zzB[UN];

#pragma unroll
    for (int i = 0; i < UN; ++i) {
        dlA[i] = dyp[(size_t)i * D_INNER];
        uuA[i] = up[(size_t)i * D_INNER];
        zzA[i] = zp[(size_t)i * 4096];
    }

#define SCAN_STEP(dlv_, uv_, zv_, t_)                                          \
    {                                                                          \
        const float* prt = pr + (size_t)(t_) * 96;                             \
        const float dlv = (dlv_);                                              \
        const float uv  = (uv_);                                               \
        const float du  = dlv * uv;                                            \
        float ysum = 0.f;                                                      \
        _Pragma("unroll")                                                      \
        for (int n = 0; n < 16; ++n) {                                         \
            const float dA = __expf(dlv * Areg[n]);                            \
            h[n] = fmaf(dA, h[n], du * prt[64 + n]);                           \
            ysum = fmaf(h[n], prt[80 + n], ysum);                              \
        }                                                                      \
        const float zv = (zv_);                                                \
        dyp[(size_t)(t_) * D_INNER] = (ysum + uv * Dd) * siluf(zv);            \
    }

    for (int t0 = 0; t0 < SEQ; t0 += 2 * UN) {
        // prefetch body B (t0+UN)
#pragma unroll
        for (int i = 0; i < UN; ++i) {
            dlB[i] = dyp[(size_t)(t0 + UN + i) * D_INNER];
            uuB[i] = up[(size_t)(t0 + UN + i) * D_INNER];
            zzB[i] = zp[(size_t)(t0 + UN + i) * 4096];
        }
        // compute body A (t0)
#pragma unroll
        for (int i = 0; i < UN; ++i) SCAN_STEP(dlA[i], uuA[i], zzA[i], t0 + i);
        // prefetch next body A (t0+2*UN)
        if (t0 + 2 * UN < SEQ) {
#pragma unroll
            for (int i = 0; i < UN; ++i) {
                dlA[i] = dyp[(size_t)(t0 + 2 * UN + i) * D_INNER];
                uuA[i] = up[(size_t)(t0 + 2 * UN + i) * D_INNER];
                zzA[i] = zp[(size_t)(t0 + 2 * UN + i) * 4096];
            }
        }
        // compute body B (t0+UN)
#pragma unroll
        for (int i = 0; i < UN; ++i) SCAN_STEP(dlB[i], uuB[i], zzB[i], t0 + UN + i);
    }
#undef SCAN_STEP
}

// ---------------------------------------------------------------------------
extern "C" void kernel_launch(void* const* d_in, const int* in_sizes, int n_in,
                              void* d_out, int out_size, void* d_ws, size_t ws_size,
                              hipStream_t stream)
{
    const float* x          = (const float*)d_in[0];
    const float* in_proj_w  = (const float*)d_in[1];
    const float* conv_w     = (const float*)d_in[2];
    const float* conv_b     = (const float*)d_in[3];
    const float* x_proj_w   = (const float*)d_in[4];
    const float* dt_proj_w  = (const float*)d_in[5];
    const float* dt_proj_b  = (const float*)d_in[6];
    const float* A_log      = (const float*)d_in[7];
    const float* Dvec       = (const float*)d_in[8];
    const float* out_proj_w = (const float*)d_in[9];
    float* out = (float*)d_out;

    char* ws = (char*)d_ws;
    float* xz    = (float*)(ws);                              // M x 4096  (64 MB)
    float* xssm  = (float*)(ws + (size_t)64 * 1024 * 1024);   // M x 2048  (32 MB)
    float* proj  = (float*)(ws + (size_t)96 * 1024 * 1024);   // M x 96    (1.5 MB)
    float* delta = (float*)(ws + (size_t)98 * 1024 * 1024);   // M x 2048  (32 MB), y in-place

    const dim3 blk(256);

    // 1) xz = x @ in_proj_w^T                (M x 4096)
    gemm_tile128<0><<<dim3(4096 / 128, M_ROWS / 128), blk, 0, stream>>>(
        x, D_MODEL, in_proj_w, D_MODEL, xz, 2 * D_INNER, D_MODEL, nullptr);

    // 2) x_ssm = silu(causal_conv1d(x_in))   (M x 2048)
    conv_silu_kernel<<<dim3((M_ROWS * D_INNER) / 256), blk, 0, stream>>>(
        xz, conv_w, conv_b, xssm);

    // 3) proj = x_ssm @ x_proj_w^T           (M x 96)
    gemm_proj_kernel<<<dim3(M_ROWS / 64), blk, 0, stream>>>(xssm, x_proj_w, proj);

    // 4) delta = softplus(dt @ dt_proj_w^T + b)  (M x 2048); dt = proj[:, 0:64]
    gemm_tile128<1><<<dim3(D_INNER / 128, M_ROWS / 128), blk, 0, stream>>>(
        proj, 96, dt_proj_w, DT_RANK, delta, D_INNER, DT_RANK, dt_proj_b);

    // 5) y = scan(...) fused with +u*D and *silu(z); in-place over delta
    scan_kernel<<<dim3(16), blk, 0, stream>>>(delta, xssm, proj, xz, A_log, Dvec);

    // 6) out = y @ out_proj_w^T              (M x 1024)
    gemm_tile128<0><<<dim3(D_MODEL / 128, M_ROWS / 128), blk, 0, stream>>>(
        delta, D_INNER, out_proj_w, D_INNER, out, D_MODEL, D_INNER, nullptr);
}

// Round 7
// 559.784 us; speedup vs baseline: 3.9341x; 3.9341x over previous
//
#include <hip/hip_runtime.h>
#include <math.h>

#define D_MODEL 1024
#define D_STATE 16
#define D_CONV  4
#define D_INNER 2048
#define DT_RANK 64
#define BATCH   2
#define SEQ     2048
#define M_ROWS  (BATCH * SEQ)   // 4096

#define TC 32                   // scan chunk length
#define NC (SEQ / TC)           // 64 chunks

typedef __attribute__((ext_vector_type(8))) short short8;
typedef __attribute__((ext_vector_type(4))) float f32x4;

__device__ __forceinline__ float softplusf(float x) {
    return (x > 20.f) ? x : log1pf(__expf(x));
}
__device__ __forceinline__ float siluf(float x) {
    return x * (1.f / (1.f + __expf(-x)));
}
__device__ __forceinline__ unsigned short f2bf(float f) {   // RNE f32->bf16
    unsigned u = __float_as_uint(f);
    u += 0x7FFFu + ((u >> 16) & 1u);
    return (unsigned short)(u >> 16);
}

// ---------------------------------------------------------------------------
// fp32 -> bf16 elementwise (8 elems/thread)
// ---------------------------------------------------------------------------
__global__ __launch_bounds__(256)
void cvt_f32_bf16(const float* __restrict__ src, unsigned short* __restrict__ dst)
{
    const size_t i = (size_t)(blockIdx.x * 256 + threadIdx.x) * 8;
    const float4 a = *(const float4*)(src + i);
    const float4 b = *(const float4*)(src + i + 4);
    short8 r;
    r[0] = (short)f2bf(a.x); r[1] = (short)f2bf(a.y);
    r[2] = (short)f2bf(a.z); r[3] = (short)f2bf(a.w);
    r[4] = (short)f2bf(b.x); r[5] = (short)f2bf(b.y);
    r[6] = (short)f2bf(b.z); r[7] = (short)f2bf(b.w);
    *(short8*)(dst + i) = r;
}

// ---------------------------------------------------------------------------
// bf16 MFMA GEMM: C(M x N fp32) = A(M x K bf16) @ W(N x K bf16)^T
// BM=BN=128, BK=32; 256 threads = 4 waves (2x2), each wave owns 64x64.
// LDS fragment-linear layout: slot = ((row>>4)*4 + kgroup)*16 + (row&15),
// 16B per slot -> staging ds_write_b128 lane-linear (conflict-free), fragment
// ds_read_b128 wave-contiguous (conflict-free).
// MFMA 16x16x32 layouts (m89-verified): A: row=l&15, k=(l>>4)*8+e;
// B: col=l&15, k=(l>>4)*8+e; D: col=l&15, row=(l>>4)*4+reg.
// ---------------------------------------------------------------------------
__global__ __launch_bounds__(256, 2)
void gemm_bf16(const unsigned short* __restrict__ A,
               const unsigned short* __restrict__ W,
               float* __restrict__ C, int ldc, int K)
{
    __shared__ short Asl[512 * 8];   // 8 KB
    __shared__ short Wsl[512 * 8];   // 8 KB

    const int tid  = threadIdx.x;
    const int lane = tid & 63;
    const int wv   = tid >> 6;       // 0..3
    const int wm   = wv >> 1;        // wave row (0..1)
    const int wn   = wv & 1;         // wave col (0..1)
    const int m0 = blockIdx.y * 128;
    const int n0 = blockIdx.x * 128;

    f32x4 acc[4][4];
#pragma unroll
    for (int ti = 0; ti < 4; ++ti)
#pragma unroll
        for (int tj = 0; tj < 4; ++tj)
            acc[ti][tj] = (f32x4){0.f, 0.f, 0.f, 0.f};

    const int kg  = lane >> 4;       // 0..3
    const int rin = lane & 15;       // row within 16-row subtile

    for (int k0 = 0; k0 < K; k0 += 32) {
        __syncthreads();             // prev iteration's frag reads complete
#pragma unroll
        for (int it = 0; it < 2; ++it) {
            const int slot = tid + it * 256;          // 0..511
            const int row  = ((slot >> 6) << 4) | (slot & 15);
            const int g    = (slot >> 4) & 3;
            *(short8*)&Asl[slot * 8] =
                *(const short8*)(A + (size_t)(m0 + row) * K + k0 + g * 8);
            *(short8*)&Wsl[slot * 8] =
                *(const short8*)(W + (size_t)(n0 + row) * K + k0 + g * 8);
        }
        __syncthreads();

        short8 af[4], wf[4];
#pragma unroll
        for (int s = 0; s < 4; ++s) {
            af[s] = *(const short8*)&Asl[(((wm * 4 + s) * 4 + kg) * 16 + rin) * 8];
            wf[s] = *(const short8*)&Wsl[(((wn * 4 + s) * 4 + kg) * 16 + rin) * 8];
        }
#pragma unroll
        for (int ti = 0; ti < 4; ++ti)
#pragma unroll
            for (int tj = 0; tj < 4; ++tj)
                acc[ti][tj] = __builtin_amdgcn_mfma_f32_16x16x32_bf16(
                    af[ti], wf[tj], acc[ti][tj], 0, 0, 0);
    }

    // epilogue: D col=lane&15, row=(lane>>4)*4+reg
    const int col0 = n0 + wn * 64 + rin;
    const int row0 = m0 + wm * 64 + kg * 4;
#pragma unroll
    for (int ti = 0; ti < 4; ++ti)
#pragma unroll
        for (int tj = 0; tj < 4; ++tj)
#pragma unroll
            for (int q = 0; q < 4; ++q)
                C[(size_t)(row0 + ti * 16 + q) * ldc + col0 + tj * 16] = acc[ti][tj][q];
}

// ---------------------------------------------------------------------------
// Generic fp32 GEMM (kept for the small delta GEMM): C = A @ W^T, EPI 1 =
// softplus(acc + bias[col]).
// ---------------------------------------------------------------------------
template <int EPI>
__global__ __launch_bounds__(256, 2)
void gemm_tile128(const float* __restrict__ A, int lda,
                  const float* __restrict__ W, int ldw,
                  float* __restrict__ C, int ldc,
                  int K, const float* __restrict__ bias)
{
    __shared__ float As[32][132];
    __shared__ float Ws[32][132];

    const int tid = threadIdx.x;
    const int tx = tid & 15;
    const int ty = tid >> 4;
    const int m0 = blockIdx.y * 128;
    const int n0 = blockIdx.x * 128;

    float acc[2][2][4][4];
#pragma unroll
    for (int im = 0; im < 2; ++im)
#pragma unroll
        for (int jm = 0; jm < 2; ++jm)
#pragma unroll
            for (int i = 0; i < 4; ++i)
#pragma unroll
                for (int j = 0; j < 4; ++j) acc[im][jm][i][j] = 0.f;

    for (int k0 = 0; k0 < K; k0 += 32) {
#pragma unroll
        for (int i = 0; i < 4; ++i) {
            const int idx = tid + i * 256;
            const int r  = idx >> 3;
            const int c4 = idx & 7;
            const float4 va = *(const float4*)(A + (size_t)(m0 + r) * lda + (k0 + c4 * 4));
            As[c4 * 4 + 0][r] = va.x;
            As[c4 * 4 + 1][r] = va.y;
            As[c4 * 4 + 2][r] = va.z;
            As[c4 * 4 + 3][r] = va.w;
            const float4 vw = *(const float4*)(W + (size_t)(n0 + r) * ldw + (k0 + c4 * 4));
            Ws[c4 * 4 + 0][r] = vw.x;
            Ws[c4 * 4 + 1][r] = vw.y;
            Ws[c4 * 4 + 2][r] = vw.z;
            Ws[c4 * 4 + 3][r] = vw.w;
        }
        __syncthreads();

#pragma unroll
        for (int kk = 0; kk < 32; ++kk) {
            float a[2][4], bfr[2][4];
            *(float4*)&a[0][0]   = *(const float4*)&As[kk][ty * 4];
            *(float4*)&a[1][0]   = *(const float4*)&As[kk][64 + ty * 4];
            *(float4*)&bfr[0][0] = *(const float4*)&Ws[kk][tx * 4];
            *(float4*)&bfr[1][0] = *(const float4*)&Ws[kk][64 + tx * 4];
#pragma unroll
            for (int im = 0; im < 2; ++im)
#pragma unroll
                for (int i = 0; i < 4; ++i)
#pragma unroll
                    for (int jm = 0; jm < 2; ++jm)
#pragma unroll
                        for (int j = 0; j < 4; ++j)
                            acc[im][jm][i][j] = fmaf(a[im][i], bfr[jm][j], acc[im][jm][i][j]);
        }
        __syncthreads();
    }

#pragma unroll
    for (int im = 0; im < 2; ++im) {
#pragma unroll
        for (int i = 0; i < 4; ++i) {
            const int row = m0 + im * 64 + ty * 4 + i;
#pragma unroll
            for (int jm = 0; jm < 2; ++jm) {
                const int col = n0 + jm * 64 + tx * 4;
                float4 v;
                v.x = acc[im][jm][i][0];
                v.y = acc[im][jm][i][1];
                v.z = acc[im][jm][i][2];
                v.w = acc[im][jm][i][3];
                if (EPI == 1) {
                    v.x = softplusf(v.x + bias[col + 0]);
                    v.y = softplusf(v.y + bias[col + 1]);
                    v.z = softplusf(v.z + bias[col + 2]);
                    v.w = softplusf(v.w + bias[col + 3]);
                }
                *(float4*)(C + (size_t)row * ldc + col) = v;
            }
        }
    }
}

// ---------------------------------------------------------------------------
// Depthwise causal conv1d (taps=4, left pad 3) + silu.
// ---------------------------------------------------------------------------
__global__ __launch_bounds__(256)
void conv_silu_kernel(const float* __restrict__ xz,
                      const float* __restrict__ cw,
                      const float* __restrict__ cb,
                      float* __restrict__ xssm)
{
    const int idx = blockIdx.x * 256 + threadIdx.x;
    const int d  = idx & (D_INNER - 1);
    const int bt = idx >> 11;
    const int t  = bt & (SEQ - 1);
    const float* p = xz + (size_t)bt * 4096 + d;
    const float w0 = cw[d * 4 + 0], w1 = cw[d * 4 + 1];
    const float w2 = cw[d * 4 + 2], w3 = cw[d * 4 + 3];
    float acc = cb[d] + w3 * p[0];
    if (t >= 1) acc += w2 * p[-4096];
    if (t >= 2) acc += w1 * p[-8192];
    if (t >= 3) acc += w0 * p[-12288];
    xssm[idx] = siluf(acc);
}

// ---------------------------------------------------------------------------
// proj(M x 96) = x_ssm(M x 2048) @ x_proj_w(96 x 2048)^T
// ---------------------------------------------------------------------------
__global__ __launch_bounds__(256, 2)
void gemm_proj_kernel(const float* __restrict__ A,
                      const float* __restrict__ W,
                      float* __restrict__ C)
{
    __shared__ float As[32][68];
    __shared__ float Ws[32][100];
    const int tid = threadIdx.x;
    const int tx = tid & 15;
    const int ty = tid >> 4;
    const int m0 = blockIdx.x * 64;

    float acc[4][6];
#pragma unroll
    for (int i = 0; i < 4; ++i)
#pragma unroll
        for (int j = 0; j < 6; ++j) acc[i][j] = 0.f;

    for (int k0 = 0; k0 < 2048; k0 += 32) {
#pragma unroll
        for (int i = 0; i < 2; ++i) {
            const int idx = tid + i * 256;
            const int r = idx >> 3, c4 = idx & 7;
            const float4 v = *(const float4*)(A + (size_t)(m0 + r) * 2048 + k0 + c4 * 4);
            As[c4 * 4 + 0][r] = v.x;
            As[c4 * 4 + 1][r] = v.y;
            As[c4 * 4 + 2][r] = v.z;
            As[c4 * 4 + 3][r] = v.w;
        }
#pragma unroll
        for (int i = 0; i < 3; ++i) {
            const int idx = tid + i * 256;
            const int r = idx >> 3, c4 = idx & 7;
            const float4 v = *(const float4*)(W + (size_t)r * 2048 + k0 + c4 * 4);
            Ws[c4 * 4 + 0][r] = v.x;
            Ws[c4 * 4 + 1][r] = v.y;
            Ws[c4 * 4 + 2][r] = v.z;
            Ws[c4 * 4 + 3][r] = v.w;
        }
        __syncthreads();
#pragma unroll
        for (int kk = 0; kk < 32; ++kk) {
            float a[4];
            *(float4*)a = *(const float4*)&As[kk][ty * 4];
            float bv[6];
#pragma unroll
            for (int j = 0; j < 6; ++j) bv[j] = Ws[kk][tx * 6 + j];
#pragma unroll
            for (int i = 0; i < 4; ++i)
#pragma unroll
                for (int j = 0; j < 6; ++j) acc[i][j] = fmaf(a[i], bv[j], acc[i][j]);
        }
        __syncthreads();
    }
#pragma unroll
    for (int i = 0; i < 4; ++i)
#pragma unroll
        for (int j = 0; j < 6; ++j)
            C[(size_t)(m0 + ty * 4 + i) * 96 + tx * 6 + j] = acc[i][j];
}

// ---------------------------------------------------------------------------
// Chunked parallel selective scan (see Round-2 notes). pass3 emits y directly
// as bf16 for the out-projection MFMA GEMM.
// ---------------------------------------------------------------------------
__global__ __launch_bounds__(256)
void scan_pass1(const float* __restrict__ delta,
                const float* __restrict__ xssm,
                const float* __restrict__ proj,
                const float* __restrict__ A_log,
                float* __restrict__ Pbuf,
                float* __restrict__ Qbuf)
{
    const int c = blockIdx.x;
    const int b = blockIdx.z;
    const int d = blockIdx.y * 256 + threadIdx.x;

    float Areg[16], P[16], Q[16];
    const float4* arow = (const float4*)(A_log + (size_t)d * 16);
#pragma unroll
    for (int q = 0; q < 4; ++q) {
        const float4 v = arow[q];
        Areg[q * 4 + 0] = -__expf(v.x);
        Areg[q * 4 + 1] = -__expf(v.y);
        Areg[q * 4 + 2] = -__expf(v.z);
        Areg[q * 4 + 3] = -__expf(v.w);
    }
#pragma unroll
    for (int n = 0; n < 16; ++n) { P[n] = 1.f; Q[n] = 0.f; }

    const float* dl = delta + ((size_t)b * SEQ + c * TC) * D_INNER + d;
    const float* up = xssm  + ((size_t)b * SEQ + c * TC) * D_INNER + d;
    const float* pr = proj  + ((size_t)b * SEQ + c * TC) * 96 + 64;

#pragma unroll 4
    for (int i = 0; i < TC; ++i) {
        const float dlv = dl[(size_t)i * D_INNER];
        const float uv  = up[(size_t)i * D_INNER];
        const float du  = dlv * uv;
        const float* prt = pr + i * 96;
#pragma unroll
        for (int n = 0; n < 16; ++n) {
            const float dA = __expf(dlv * Areg[n]);
            Q[n] = fmaf(dA, Q[n], du * prt[n]);
            P[n] *= dA;
        }
    }

    const size_t base = (((size_t)b * NC + c) * 16) * D_INNER + d;
#pragma unroll
    for (int n = 0; n < 16; ++n) {
        Pbuf[base + (size_t)n * D_INNER] = P[n];
        Qbuf[base + (size_t)n * D_INNER] = Q[n];
    }
}

__global__ __launch_bounds__(256)
void scan_pass2(const float* __restrict__ Pbuf,
                float* __restrict__ Qbuf)
{
    const int i = blockIdx.x * 256 + threadIdx.x;
    const int d = i & (D_INNER - 1);
    const int n = (i >> 11) & 15;
    const int b = i >> 15;

    float hs = 0.f;
    const size_t stride = (size_t)16 * D_INNER;
    size_t idx = ((size_t)b * NC * 16 + n) * D_INNER + d;
    for (int c = 0; c < NC; ++c) {
        const float Pv = Pbuf[idx];
        const float Qv = Qbuf[idx];
        Qbuf[idx] = hs;
        hs = fmaf(Pv, hs, Qv);
        idx += stride;
    }
}

__global__ __launch_bounds__(256)
void scan_pass3(const float* __restrict__ delta,
                const float* __restrict__ xssm,
                const float* __restrict__ proj,
                const float* __restrict__ xz,
                const float* __restrict__ A_log,
                const float* __restrict__ Dvec,
                const float* __restrict__ Qbuf,
                unsigned short* __restrict__ ybf)
{
    const int c = blockIdx.x;
    const int b = blockIdx.z;
    const int d = blockIdx.y * 256 + threadIdx.x;

    float Areg[16], h[16];
    const float4* arow = (const float4*)(A_log + (size_t)d * 16);
#pragma unroll
    for (int q = 0; q < 4; ++q) {
        const float4 v = arow[q];
        Areg[q * 4 + 0] = -__expf(v.x);
        Areg[q * 4 + 1] = -__expf(v.y);
        Areg[q * 4 + 2] = -__expf(v.z);
        Areg[q * 4 + 3] = -__expf(v.w);
    }
    const size_t hbase = (((size_t)b * NC + c) * 16) * D_INNER + d;
#pragma unroll
    for (int n = 0; n < 16; ++n) h[n] = Qbuf[hbase + (size_t)n * D_INNER];

    const float Dd = Dvec[d];
    const float* dlp = delta + ((size_t)b * SEQ + c * TC) * D_INNER + d;
    const float* up  = xssm  + ((size_t)b * SEQ + c * TC) * D_INNER + d;
    const float* zp  = xz    + ((size_t)b * SEQ + c * TC) * 4096 + 2048 + d;
    const float* pr  = proj  + ((size_t)b * SEQ + c * TC) * 96 + 64;
    unsigned short* yp = ybf + ((size_t)b * SEQ + c * TC) * D_INNER + d;

#pragma unroll 4
    for (int i = 0; i < TC; ++i) {
        const float dlv = dlp[(size_t)i * D_INNER];
        const float uv  = up[(size_t)i * D_INNER];
        const float zv  = zp[(size_t)i * 4096];
        const float du  = dlv * uv;
        const float* prt = pr + i * 96;
        float ysum = 0.f;
#pragma unroll
        for (int n = 0; n < 16; ++n) {
            const float dA = __expf(dlv * Areg[n]);
            h[n] = fmaf(dA, h[n], du * prt[n]);
            ysum = fmaf(h[n], prt[16 + n], ysum);
        }
        yp[(size_t)i * D_INNER] = f2bf((ysum + uv * Dd) * siluf(zv));
    }
}

// ---------------------------------------------------------------------------
// Workspace layout (162 MB total == bound proven by Round-2 pass):
//   [  0..64 )  xz      fp32 M x 4096        live steps 1-5c
//   [ 64..96 )  xssm    fp32 M x 2048        live steps 2-5c
//   [ 96..98 )  proj    fp32 M x 96          live steps 3-5c
//   [ 98..130)  delta   fp32 M x 2048        live steps 4-5c
//   [130..146)  xb(0-1) | Pbuf(5a-5b) | ybf(5c-6)            disjoint
//   [146..162)  wbi(0-1) | Qbuf(5a-5c) | wbo(post-5c .. 6)   disjoint
// wbo's cvt launch is AFTER scan_pass3 (stream order makes the aliasing safe).
// ---------------------------------------------------------------------------
extern "C" void kernel_launch(void* const* d_in, const int* in_sizes, int n_in,
                              void* d_out, int out_size, void* d_ws, size_t ws_size,
                              hipStream_t stream)
{
    const float* x          = (const float*)d_in[0];
    const float* in_proj_w  = (const float*)d_in[1];
    const float* conv_w     = (const float*)d_in[2];
    const float* conv_b     = (const float*)d_in[3];
    const float* x_proj_w   = (const float*)d_in[4];
    const float* dt_proj_w  = (const float*)d_in[5];
    const float* dt_proj_b  = (const float*)d_in[6];
    const float* A_log      = (const float*)d_in[7];
    const float* Dvec       = (const float*)d_in[8];
    const float* out_proj_w = (const float*)d_in[9];
    float* out = (float*)d_out;

    char* ws = (char*)d_ws;
    const size_t MB = 1024 * 1024;
    float* xz    = (float*)(ws);
    float* xssm  = (float*)(ws + 64  * MB);
    float* proj  = (float*)(ws + 96  * MB);
    float* delta = (float*)(ws + 98  * MB);
    unsigned short* xb  = (unsigned short*)(ws + 130 * MB);   // steps 0-1
    float* Pbuf  = (float*)(ws + 130 * MB);                   // steps 5a-5b
    unsigned short* ybf = (unsigned short*)(ws + 130 * MB);   // steps 5c-6
    unsigned short* wbi = (unsigned short*)(ws + 146 * MB);   // steps 0-1
    float* Qbuf  = (float*)(ws + 146 * MB);                   // steps 5a-5c
    unsigned short* wbo = (unsigned short*)(ws + 146 * MB);   // post-5c..6

    const dim3 blk(256);

    // 0) pre-convert bf16 operands for GEMM1
    cvt_f32_bf16<<<dim3((M_ROWS * D_MODEL) / (256 * 8)), blk, 0, stream>>>(x, xb);
    cvt_f32_bf16<<<dim3((2 * D_INNER * D_MODEL) / (256 * 8)), blk, 0, stream>>>(in_proj_w, wbi);

    // 1) xz = x @ in_proj_w^T                (M x 4096, bf16 MFMA)
    gemm_bf16<<<dim3(4096 / 128, M_ROWS / 128), blk, 0, stream>>>(
        xb, wbi, xz, 2 * D_INNER, D_MODEL);

    // 2) x_ssm = silu(causal_conv1d(x_in))   (M x 2048)
    conv_silu_kernel<<<dim3((M_ROWS * D_INNER) / 256), blk, 0, stream>>>(
        xz, conv_w, conv_b, xssm);

    // 3) proj = x_ssm @ x_proj_w^T           (M x 96, fp32)
    gemm_proj_kernel<<<dim3(M_ROWS / 64), blk, 0, stream>>>(xssm, x_proj_w, proj);

    // 4) delta = softplus(dt @ dt_proj_w^T + b)  (M x 2048, fp32)
    gemm_tile128<1><<<dim3(D_INNER / 128, M_ROWS / 128), blk, 0, stream>>>(
        proj, 96, dt_proj_w, DT_RANK, delta, D_INNER, DT_RANK, dt_proj_b);

    // 5) chunked parallel scan (fused skip + gate), y emitted as bf16
    scan_pass1<<<dim3(NC, D_INNER / 256, BATCH), blk, 0, stream>>>(
        delta, xssm, proj, A_log, Pbuf, Qbuf);
    scan_pass2<<<dim3((BATCH * D_INNER * 16) / 256), blk, 0, stream>>>(Pbuf, Qbuf);
    scan_pass3<<<dim3(NC, D_INNER / 256, BATCH), blk, 0, stream>>>(
        delta, xssm, proj, xz, A_log, Dvec, Qbuf, ybf);

    // 5d) out_proj_w -> bf16 (Qbuf region is dead now; stream-ordered alias)
    cvt_f32_bf16<<<dim3((D_MODEL * D_INNER) / (256 * 8)), blk, 0, stream>>>(out_proj_w, wbo);

    // 6) out = y @ out_proj_w^T              (M x 1024, bf16 MFMA)
    gemm_bf16<<<dim3(D_MODEL / 128, M_ROWS / 128), blk, 0, stream>>>(
        ybf, wbo, out, D_MODEL, D_INNER);
}

// Round 9
// 429.839 us; speedup vs baseline: 5.1234x; 1.3023x over previous
//
#include <hip/hip_runtime.h>
#include <math.h>

#define D_MODEL 1024
#define D_STATE 16
#define D_CONV  4
#define D_INNER 2048
#define DT_RANK 64
#define BATCH   2
#define SEQ     2048
#define M_ROWS  (BATCH * SEQ)   // 4096

#define TC 32                   // scan chunk length
#define NC (SEQ / TC)           // 64 chunks

#define KS  8                   // proj split-K factor
#define KCH (2048 / KS)         // 256

typedef __attribute__((ext_vector_type(8))) short short8;
typedef __attribute__((ext_vector_type(4))) float f32x4;

__device__ __forceinline__ float softplusf(float x) {
    return (x > 20.f) ? x : log1pf(__expf(x));
}
__device__ __forceinline__ float siluf(float x) {
    return x * (1.f / (1.f + __expf(-x)));
}
__device__ __forceinline__ unsigned short f2bf(float f) {   // RNE f32->bf16
    unsigned u = __float_as_uint(f);
    u += 0x7FFFu + ((u >> 16) & 1u);
    return (unsigned short)(u >> 16);
}

// ---------------------------------------------------------------------------
// fp32 -> bf16 elementwise (8 elems/thread)
// ---------------------------------------------------------------------------
__global__ __launch_bounds__(256)
void cvt_f32_bf16(const float* __restrict__ src, unsigned short* __restrict__ dst)
{
    const size_t i = (size_t)(blockIdx.x * 256 + threadIdx.x) * 8;
    const float4 a = *(const float4*)(src + i);
    const float4 b = *(const float4*)(src + i + 4);
    short8 r;
    r[0] = (short)f2bf(a.x); r[1] = (short)f2bf(a.y);
    r[2] = (short)f2bf(a.z); r[3] = (short)f2bf(a.w);
    r[4] = (short)f2bf(b.x); r[5] = (short)f2bf(b.y);
    r[6] = (short)f2bf(b.z); r[7] = (short)f2bf(b.w);
    *(short8*)(dst + i) = r;
}

// ---------------------------------------------------------------------------
// bf16 MFMA GEMM: C(M x N fp32) = A(M x K bf16) @ W(N x K bf16)^T
// BM=BN=128, BK=32; 256 threads = 4 waves (2x2), each wave owns 64x64.
// LDS fragment-linear layout: slot = ((row>>4)*4 + kgroup)*16 + (row&15).
// MFMA 16x16x32 layouts (m89-verified): A: row=l&15, k=(l>>4)*8+e;
// B: col=l&15, k=(l>>4)*8+e; D: col=l&15, row=(l>>4)*4+reg.
// ---------------------------------------------------------------------------
__global__ __launch_bounds__(256, 2)
void gemm_bf16(const unsigned short* __restrict__ A,
               const unsigned short* __restrict__ W,
               float* __restrict__ C, int ldc, int K)
{
    __shared__ short Asl[512 * 8];   // 8 KB
    __shared__ short Wsl[512 * 8];   // 8 KB

    const int tid  = threadIdx.x;
    const int lane = tid & 63;
    const int wv   = tid >> 6;       // 0..3
    const int wm   = wv >> 1;        // wave row (0..1)
    const int wn   = wv & 1;         // wave col (0..1)
    const int m0 = blockIdx.y * 128;
    const int n0 = blockIdx.x * 128;

    f32x4 acc[4][4];
#pragma unroll
    for (int ti = 0; ti < 4; ++ti)
#pragma unroll
        for (int tj = 0; tj < 4; ++tj)
            acc[ti][tj] = (f32x4){0.f, 0.f, 0.f, 0.f};

    const int kg  = lane >> 4;       // 0..3
    const int rin = lane & 15;       // row within 16-row subtile

    for (int k0 = 0; k0 < K; k0 += 32) {
        __syncthreads();             // prev iteration's frag reads complete
#pragma unroll
        for (int it = 0; it < 2; ++it) {
            const int slot = tid + it * 256;          // 0..511
            const int row  = ((slot >> 6) << 4) | (slot & 15);
            const int g    = (slot >> 4) & 3;
            *(short8*)&Asl[slot * 8] =
                *(const short8*)(A + (size_t)(m0 + row) * K + k0 + g * 8);
            *(short8*)&Wsl[slot * 8] =
                *(const short8*)(W + (size_t)(n0 + row) * K + k0 + g * 8);
        }
        __syncthreads();

        short8 af[4], wf[4];
#pragma unroll
        for (int s = 0; s < 4; ++s) {
            af[s] = *(const short8*)&Asl[(((wm * 4 + s) * 4 + kg) * 16 + rin) * 8];
            wf[s] = *(const short8*)&Wsl[(((wn * 4 + s) * 4 + kg) * 16 + rin) * 8];
        }
#pragma unroll
        for (int ti = 0; ti < 4; ++ti)
#pragma unroll
            for (int tj = 0; tj < 4; ++tj)
                acc[ti][tj] = __builtin_amdgcn_mfma_f32_16x16x32_bf16(
                    af[ti], wf[tj], acc[ti][tj], 0, 0, 0);
    }

    // epilogue: D col=lane&15, row=(lane>>4)*4+reg
    const int col0 = n0 + wn * 64 + rin;
    const int row0 = m0 + wm * 64 + kg * 4;
#pragma unroll
    for (int ti = 0; ti < 4; ++ti)
#pragma unroll
        for (int tj = 0; tj < 4; ++tj)
#pragma unroll
            for (int q = 0; q < 4; ++q)
                C[(size_t)(row0 + ti * 16 + q) * ldc + col0 + tj * 16] = acc[ti][tj][q];
}

// ---------------------------------------------------------------------------
// Generic fp32 GEMM (kept for the small delta GEMM): C = A @ W^T, EPI 1 =
// softplus(acc + bias[col]).
// ---------------------------------------------------------------------------
template <int EPI>
__global__ __launch_bounds__(256, 2)
void gemm_tile128(const float* __restrict__ A, int lda,
                  const float* __restrict__ W, int ldw,
                  float* __restrict__ C, int ldc,
                  int K, const float* __restrict__ bias)
{
    __shared__ float As[32][132];
    __shared__ float Ws[32][132];

    const int tid = threadIdx.x;
    const int tx = tid & 15;
    const int ty = tid >> 4;
    const int m0 = blockIdx.y * 128;
    const int n0 = blockIdx.x * 128;

    float acc[2][2][4][4];
#pragma unroll
    for (int im = 0; im < 2; ++im)
#pragma unroll
        for (int jm = 0; jm < 2; ++jm)
#pragma unroll
            for (int i = 0; i < 4; ++i)
#pragma unroll
                for (int j = 0; j < 4; ++j) acc[im][jm][i][j] = 0.f;

    for (int k0 = 0; k0 < K; k0 += 32) {
#pragma unroll
        for (int i = 0; i < 4; ++i) {
            const int idx = tid + i * 256;
            const int r  = idx >> 3;
            const int c4 = idx & 7;
            const float4 va = *(const float4*)(A + (size_t)(m0 + r) * lda + (k0 + c4 * 4));
            As[c4 * 4 + 0][r] = va.x;
            As[c4 * 4 + 1][r] = va.y;
            As[c4 * 4 + 2][r] = va.z;
            As[c4 * 4 + 3][r] = va.w;
            const float4 vw = *(const float4*)(W + (size_t)(n0 + r) * ldw + (k0 + c4 * 4));
            Ws[c4 * 4 + 0][r] = vw.x;
            Ws[c4 * 4 + 1][r] = vw.y;
            Ws[c4 * 4 + 2][r] = vw.z;
            Ws[c4 * 4 + 3][r] = vw.w;
        }
        __syncthreads();

#pragma unroll
        for (int kk = 0; kk < 32; ++kk) {
            float a[2][4], bfr[2][4];
            *(float4*)&a[0][0]   = *(const float4*)&As[kk][ty * 4];
            *(float4*)&a[1][0]   = *(const float4*)&As[kk][64 + ty * 4];
            *(float4*)&bfr[0][0] = *(const float4*)&Ws[kk][tx * 4];
            *(float4*)&bfr[1][0] = *(const float4*)&Ws[kk][64 + tx * 4];
#pragma unroll
            for (int im = 0; im < 2; ++im)
#pragma unroll
                for (int i = 0; i < 4; ++i)
#pragma unroll
                    for (int jm = 0; jm < 2; ++jm)
#pragma unroll
                        for (int j = 0; j < 4; ++j)
                            acc[im][jm][i][j] = fmaf(a[im][i], bfr[jm][j], acc[im][jm][i][j]);
        }
        __syncthreads();
    }

#pragma unroll
    for (int im = 0; im < 2; ++im) {
#pragma unroll
        for (int i = 0; i < 4; ++i) {
            const int row = m0 + im * 64 + ty * 4 + i;
#pragma unroll
            for (int jm = 0; jm < 2; ++jm) {
                const int col = n0 + jm * 64 + tx * 4;
                float4 v;
                v.x = acc[im][jm][i][0];
                v.y = acc[im][jm][i][1];
                v.z = acc[im][jm][i][2];
                v.w = acc[im][jm][i][3];
                if (EPI == 1) {
                    v.x = softplusf(v.x + bias[col + 0]);
                    v.y = softplusf(v.y + bias[col + 1]);
                    v.z = softplusf(v.z + bias[col + 2]);
                    v.w = softplusf(v.w + bias[col + 3]);
                }
                *(float4*)(C + (size_t)row * ldc + col) = v;
            }
        }
    }
}

// ---------------------------------------------------------------------------
// Depthwise causal conv1d (taps=4, left pad 3) + silu.
// ---------------------------------------------------------------------------
__global__ __launch_bounds__(256)
void conv_silu_kernel(const float* __restrict__ xz,
                      const float* __restrict__ cw,
                      const float* __restrict__ cb,
                      float* __restrict__ xssm)
{
    const int idx = blockIdx.x * 256 + threadIdx.x;
    const int d  = idx & (D_INNER - 1);
    const int bt = idx >> 11;
    const int t  = bt & (SEQ - 1);
    const float* p = xz + (size_t)bt * 4096 + d;
    const float w0 = cw[d * 4 + 0], w1 = cw[d * 4 + 1];
    const float w2 = cw[d * 4 + 2], w3 = cw[d * 4 + 3];
    float acc = cb[d] + w3 * p[0];
    if (t >= 1) acc += w2 * p[-4096];
    if (t >= 2) acc += w1 * p[-8192];
    if (t >= 3) acc += w0 * p[-12288];
    xssm[idx] = siluf(acc);
}

// ---------------------------------------------------------------------------
// proj split-K pass 1: partial[ks][m][96] = x_ssm[m, ks*256:(ks+1)*256] @ W^T
// Grid (M/64, KS) = 512 blocks; BM=64, BN=96, BK=32 inner.
// ---------------------------------------------------------------------------
__global__ __launch_bounds__(256, 2)
void gemm_proj_splitk(const float* __restrict__ A,
                      const float* __restrict__ W,
                      float* __restrict__ partial)
{
    __shared__ float As[32][68];
    __shared__ float Ws[32][100];
    const int tid = threadIdx.x;
    const int tx = tid & 15;
    const int ty = tid >> 4;
    const int m0 = blockIdx.x * 64;
    const int ks = blockIdx.y;

    float acc[4][6];
#pragma unroll
    for (int i = 0; i < 4; ++i)
#pragma unroll
        for (int j = 0; j < 6; ++j) acc[i][j] = 0.f;

    for (int k0 = ks * KCH; k0 < (ks + 1) * KCH; k0 += 32) {
#pragma unroll
        for (int i = 0; i < 2; ++i) {               // A: 64x32 = 512 float4
            const int idx = tid + i * 256;
            const int r = idx >> 3, c4 = idx & 7;
            const float4 v = *(const float4*)(A + (size_t)(m0 + r) * 2048 + k0 + c4 * 4);
            As[c4 * 4 + 0][r] = v.x;
            As[c4 * 4 + 1][r] = v.y;
            As[c4 * 4 + 2][r] = v.z;
            As[c4 * 4 + 3][r] = v.w;
        }
#pragma unroll
        for (int i = 0; i < 3; ++i) {               // W: 96x32 = 768 float4
            const int idx = tid + i * 256;
            const int r = idx >> 3, c4 = idx & 7;
            const float4 v = *(const float4*)(W + (size_t)r * 2048 + k0 + c4 * 4);
            Ws[c4 * 4 + 0][r] = v.x;
            Ws[c4 * 4 + 1][r] = v.y;
            Ws[c4 * 4 + 2][r] = v.z;
            Ws[c4 * 4 + 3][r] = v.w;
        }
        __syncthreads();
#pragma unroll
        for (int kk = 0; kk < 32; ++kk) {
            float a[4];
            *(float4*)a = *(const float4*)&As[kk][ty * 4];
            float bv[6];
#pragma unroll
            for (int j = 0; j < 6; ++j) bv[j] = Ws[kk][tx * 6 + j];
#pragma unroll
            for (int i = 0; i < 4; ++i)
#pragma unroll
                for (int j = 0; j < 6; ++j) acc[i][j] = fmaf(a[i], bv[j], acc[i][j]);
        }
        __syncthreads();
    }

    float* outp = partial + (size_t)ks * M_ROWS * 96;
#pragma unroll
    for (int i = 0; i < 4; ++i)
#pragma unroll
        for (int j = 0; j < 6; ++j)
            outp[(size_t)(m0 + ty * 4 + i) * 96 + tx * 6 + j] = acc[i][j];
}

// proj split-K pass 2: proj[idx] = sum_ks partial[ks][idx]
__global__ __launch_bounds__(256)
void proj_reduce(const float* __restrict__ partial, float* __restrict__ proj)
{
    const int idx = blockIdx.x * 256 + threadIdx.x;   // over M_ROWS*96
    float s = 0.f;
#pragma unroll
    for (int ks = 0; ks < KS; ++ks)
        s += partial[(size_t)ks * M_ROWS * 96 + idx];
    proj[idx] = s;
}

// ---------------------------------------------------------------------------
// Chunked parallel selective scan (see Round-2 notes). pass3 emits y directly
// as bf16 for the out-projection MFMA GEMM.
// ---------------------------------------------------------------------------
__global__ __launch_bounds__(256)
void scan_pass1(const float* __restrict__ delta,
                const float* __restrict__ xssm,
                const float* __restrict__ proj,
                const float* __restrict__ A_log,
                float* __restrict__ Pbuf,
                float* __restrict__ Qbuf)
{
    const int c = blockIdx.x;
    const int b = blockIdx.z;
    const int d = blockIdx.y * 256 + threadIdx.x;

    float Areg[16], P[16], Q[16];
    const float4* arow = (const float4*)(A_log + (size_t)d * 16);
#pragma unroll
    for (int q = 0; q < 4; ++q) {
        const float4 v = arow[q];
        Areg[q * 4 + 0] = -__expf(v.x);
        Areg[q * 4 + 1] = -__expf(v.y);
        Areg[q * 4 + 2] = -__expf(v.z);
        Areg[q * 4 + 3] = -__expf(v.w);
    }
#pragma unroll
    for (int n = 0; n < 16; ++n) { P[n] = 1.f; Q[n] = 0.f; }

    const float* dl = delta + ((size_t)b * SEQ + c * TC) * D_INNER + d;
    const float* up = xssm  + ((size_t)b * SEQ + c * TC) * D_INNER + d;
    const float* pr = proj  + ((size_t)b * SEQ + c * TC) * 96 + 64;

#pragma unroll 4
    for (int i = 0; i < TC; ++i) {
        const float dlv = dl[(size_t)i * D_INNER];
        const float uv  = up[(size_t)i * D_INNER];
        const float du  = dlv * uv;
        const float* prt = pr + i * 96;
#pragma unroll
        for (int n = 0; n < 16; ++n) {
            const float dA = __expf(dlv * Areg[n]);
            Q[n] = fmaf(dA, Q[n], du * prt[n]);
            P[n] *= dA;
        }
    }

    const size_t base = (((size_t)b * NC + c) * 16) * D_INNER + d;
#pragma unroll
    for (int n = 0; n < 16; ++n) {
        Pbuf[base + (size_t)n * D_INNER] = P[n];
        Qbuf[base + (size_t)n * D_INNER] = Q[n];
    }
}

__global__ __launch_bounds__(256)
void scan_pass2(const float* __restrict__ Pbuf,
                float* __restrict__ Qbuf)
{
    const int i = blockIdx.x * 256 + threadIdx.x;
    const int d = i & (D_INNER - 1);
    const int n = (i >> 11) & 15;
    const int b = i >> 15;

    float hs = 0.f;
    const size_t stride = (size_t)16 * D_INNER;
    size_t idx = ((size_t)b * NC * 16 + n) * D_INNER + d;
    for (int c = 0; c < NC; ++c) {
        const float Pv = Pbuf[idx];
        const float Qv = Qbuf[idx];
        Qbuf[idx] = hs;
        hs = fmaf(Pv, hs, Qv);
        idx += stride;
    }
}

__global__ __launch_bounds__(256)
void scan_pass3(const float* __restrict__ delta,
                const float* __restrict__ xssm,
                const float* __restrict__ proj,
                const float* __restrict__ xz,
                const float* __restrict__ A_log,
                const float* __restrict__ Dvec,
                const float* __restrict__ Qbuf,
                unsigned short* __restrict__ ybf)
{
    const int c = blockIdx.x;
    const int b = blockIdx.z;
    const int d = blockIdx.y * 256 + threadIdx.x;

    float Areg[16], h[16];
    const float4* arow = (const float4*)(A_log + (size_t)d * 16);
#pragma unroll
    for (int q = 0; q < 4; ++q) {
        const float4 v = arow[q];
        Areg[q * 4 + 0] = -__expf(v.x);
        Areg[q * 4 + 1] = -__expf(v.y);
        Areg[q * 4 + 2] = -__expf(v.z);
        Areg[q * 4 + 3] = -__expf(v.w);
    }
    const size_t hbase = (((size_t)b * NC + c) * 16) * D_INNER + d;
#pragma unroll
    for (int n = 0; n < 16; ++n) h[n] = Qbuf[hbase + (size_t)n * D_INNER];

    const float Dd = Dvec[d];
    const float* dlp = delta + ((size_t)b * SEQ + c * TC) * D_INNER + d;
    const float* up  = xssm  + ((size_t)b * SEQ + c * TC) * D_INNER + d;
    const float* zp  = xz    + ((size_t)b * SEQ + c * TC) * 4096 + 2048 + d;
    const float* pr  = proj  + ((size_t)b * SEQ + c * TC) * 96 + 64;
    unsigned short* yp = ybf + ((size_t)b * SEQ + c * TC) * D_INNER + d;

#pragma unroll 4
    for (int i = 0; i < TC; ++i) {
        const float dlv = dlp[(size_t)i * D_INNER];
        const float uv  = up[(size_t)i * D_INNER];
        const float zv  = zp[(size_t)i * 4096];
        const float du  = dlv * uv;
        const float* prt = pr + i * 96;
        float ysum = 0.f;
#pragma unroll
        for (int n = 0; n < 16; ++n) {
            const float dA = __expf(dlv * Areg[n]);
            h[n] = fmaf(dA, h[n], du * prt[n]);
            ysum = fmaf(h[n], prt[16 + n], ysum);
        }
        yp[(size_t)i * D_INNER] = f2bf((ysum + uv * Dd) * siluf(zv));
    }
}

// ---------------------------------------------------------------------------
// Workspace layout (162 MB total == bound proven by Round-2/7 passes):
//   [  0..64 )  xz      fp32 M x 4096        live steps 1-5c
//   [ 64..96 )  xssm    fp32 M x 2048        live steps 2-5c
//   [ 96..98 )  proj    fp32 M x 96          live steps 3b-5c
//   [ 98..130)  delta   fp32 M x 2048        live steps 4-5c
//   [130..146)  xb(0-1) | partial(3a-3b) | Pbuf(5a-5b) | ybf(5c-6)   disjoint
//   [146..162)  wbi(0-1) | Qbuf(5a-5c) | wbo(post-5c..6)             disjoint
// ---------------------------------------------------------------------------
extern "C" void kernel_launch(void* const* d_in, const int* in_sizes, int n_in,
                              void* d_out, int out_size, void* d_ws, size_t ws_size,
                              hipStream_t stream)
{
    const float* x          = (const float*)d_in[0];
    const float* in_proj_w  = (const float*)d_in[1];
    const float* conv_w     = (const float*)d_in[2];
    const float* conv_b     = (const float*)d_in[3];
    const float* x_proj_w   = (const float*)d_in[4];
    const float* dt_proj_w  = (const float*)d_in[5];
    const float* dt_proj_b  = (const float*)d_in[6];
    const float* A_log      = (const float*)d_in[7];
    const float* Dvec       = (const float*)d_in[8];
    const float* out_proj_w = (const float*)d_in[9];
    float* out = (float*)d_out;

    char* ws = (char*)d_ws;
    const size_t MB = 1024 * 1024;
    float* xz    = (float*)(ws);
    float* xssm  = (float*)(ws + 64  * MB);
    float* proj  = (float*)(ws + 96  * MB);
    float* delta = (float*)(ws + 98  * MB);
    unsigned short* xb      = (unsigned short*)(ws + 130 * MB);  // steps 0-1
    float*          partial = (float*)(ws + 130 * MB);           // steps 3a-3b
    float*          Pbuf    = (float*)(ws + 130 * MB);           // steps 5a-5b
    unsigned short* ybf     = (unsigned short*)(ws + 130 * MB);  // steps 5c-6
    unsigned short* wbi     = (unsigned short*)(ws + 146 * MB);  // steps 0-1
    float*          Qbuf    = (float*)(ws + 146 * MB);           // steps 5a-5c
    unsigned short* wbo     = (unsigned short*)(ws + 146 * MB);  // post-5c..6

    const dim3 blk(256);

    // 0) pre-convert bf16 operands for GEMM1
    cvt_f32_bf16<<<dim3((M_ROWS * D_MODEL) / (256 * 8)), blk, 0, stream>>>(x, xb);
    cvt_f32_bf16<<<dim3((2 * D_INNER * D_MODEL) / (256 * 8)), blk, 0, stream>>>(in_proj_w, wbi);

    // 1) xz = x @ in_proj_w^T                (M x 4096, bf16 MFMA)
    gemm_bf16<<<dim3(4096 / 128, M_ROWS / 128), blk, 0, stream>>>(
        xb, wbi, xz, 2 * D_INNER, D_MODEL);

    // 2) x_ssm = silu(causal_conv1d(x_in))   (M x 2048)
    conv_silu_kernel<<<dim3((M_ROWS * D_INNER) / 256), blk, 0, stream>>>(
        xz, conv_w, conv_b, xssm);

    // 3) proj = x_ssm @ x_proj_w^T           (M x 96, fp32 split-K)
    gemm_proj_splitk<<<dim3(M_ROWS / 64, KS), blk, 0, stream>>>(xssm, x_proj_w, partial);
    proj_reduce<<<dim3((M_ROWS * 96) / 256), blk, 0, stream>>>(partial, proj);

    // 4) delta = softplus(dt @ dt_proj_w^T + b)  (M x 2048, fp32)
    gemm_tile128<1><<<dim3(D_INNER / 128, M_ROWS / 128), blk, 0, stream>>>(
        proj, 96, dt_proj_w, DT_RANK, delta, D_INNER, DT_RANK, dt_proj_b);

    // 5) chunked parallel scan (fused skip + gate), y emitted as bf16
    scan_pass1<<<dim3(NC, D_INNER / 256, BATCH), blk, 0, stream>>>(
        delta, xssm, proj, A_log, Pbuf, Qbuf);
    scan_pass2<<<dim3((BATCH * D_INNER * 16) / 256), blk, 0, stream>>>(Pbuf, Qbuf);
    scan_pass3<<<dim3(NC, D_INNER / 256, BATCH), blk, 0, stream>>>(
        delta, xssm, proj, xz, A_log, Dvec, Qbuf, ybf);

    // 5d) out_proj_w -> bf16 (Qbuf region is dead now; stream-ordered alias)
    cvt_f32_bf16<<<dim3((D_MODEL * D_INNER) / (256 * 8)), blk, 0, stream>>>(out_proj_w, wbo);

    // 6) out = y @ out_proj_w^T              (M x 1024, bf16 MFMA)
    gemm_bf16<<<dim3(D_MODEL / 128, M_ROWS / 128), blk, 0, stream>>>(
        ybf, wbo, out, D_MODEL, D_INNER);
}